// Round 1
// baseline (2335.813 us; speedup 1.0000x reference)
//
#include <hip/hip_runtime.h>
#include <cfloat>

#define N_PTS 4096
#define NB    4
#define KNN   20
#define EPSB  1e-5f

#define BT 64
#define KT 16

// ---------------------------------------------------------------------------
// Generic K-major GEMM: Out[row][col] = sum_k Mr[k][row] * Mc[k][col]
// Both operands K-major (k stride = ld). 64x64 tile, 256 threads, 4x4 micro.
// mode 0: plain                      (q:    Out[j][o], point-major)
// mode 1: val += aux1[col]           (p:    shift on o=col)
// mode 2: lrelu(val + aux1[row])     (y4:   shift on o=row, channel-major)
// mode 3: aux1[row]+aux2[col]-2*val  (dist: squared distance)
// ---------------------------------------------------------------------------
__global__ __launch_bounds__(256)
void gemm_kmajor(const float* __restrict__ Mr, const float* __restrict__ Mc,
                 float* __restrict__ Out,
                 const float* __restrict__ aux1, const float* __restrict__ aux2,
                 int K, int ldr, int ldc, int ldo,
                 long bsR, long bsC, long bsO,
                 int mode)
{
    __shared__ float Rs[KT][BT];
    __shared__ float Cs[KT][BT];
    int bz = blockIdx.z;
    const float* mr = Mr + bz * bsR;
    const float* mc = Mc + bz * bsC;
    float* outp = Out + bz * bsO;
    int row0 = blockIdx.x * BT;
    int col0 = blockIdx.y * BT;
    int tid = threadIdx.x;
    int tx = tid & 15, ty = tid >> 4;

    float acc[4][4];
#pragma unroll
    for (int r = 0; r < 4; r++)
#pragma unroll
        for (int c = 0; c < 4; c++) acc[r][c] = 0.f;

    for (int k0 = 0; k0 < K; k0 += KT) {
#pragma unroll
        for (int l = 0; l < (KT * BT) / 256; l++) {
            int e = l * 256 + tid;
            int kk = e >> 6, r = e & 63;
            int kg = k0 + kk;
            float rv = 0.f, cv = 0.f;
            if (kg < K) {
                rv = mr[(long)kg * ldr + row0 + r];
                cv = mc[(long)kg * ldc + col0 + r];
            }
            Rs[kk][r] = rv;
            Cs[kk][r] = cv;
        }
        __syncthreads();
#pragma unroll
        for (int kk = 0; kk < KT; kk++) {
            float rv[4], cv[4];
#pragma unroll
            for (int e = 0; e < 4; e++) rv[e] = Rs[kk][ty * 4 + e];
#pragma unroll
            for (int e = 0; e < 4; e++) cv[e] = Cs[kk][tx * 4 + e];
#pragma unroll
            for (int r = 0; r < 4; r++)
#pragma unroll
                for (int c = 0; c < 4; c++)
                    acc[r][c] = fmaf(rv[r], cv[c], acc[r][c]);
        }
        __syncthreads();
    }

    int orow = row0 + ty * 4;
    int ocol = col0 + tx * 4;
#pragma unroll
    for (int r = 0; r < 4; r++) {
        float vv[4];
#pragma unroll
        for (int c = 0; c < 4; c++) {
            float val = acc[r][c];
            if (mode == 1) {
                val += aux1[ocol + c];
            } else if (mode == 2) {
                val += aux1[orow + r];
                val = val >= 0.f ? val : 0.2f * val;
            } else if (mode == 3) {
                val = aux1[orow + r] + aux2[ocol + c] - 2.f * val;
            }
            vv[c] = val;
        }
        float4 v4;
        v4.x = vv[0]; v4.y = vv[1]; v4.z = vv[2]; v4.w = vv[3];
        *(float4*)(outp + (long)(orow + r) * ldo + ocol) = v4;
    }
}

// ---------------------------------------------------------------------------
// Top-20 smallest per row of D (one batch). One block per row.
// ---------------------------------------------------------------------------
__global__ __launch_bounds__(256)
void topk_kernel(const float* __restrict__ D, int* __restrict__ idxOut)
{
    __shared__ float ds[N_PTS];
    __shared__ float rv[256];
    __shared__ int   ri[256];
    int i = blockIdx.x;
    int t = threadIdx.x;
    const float* row = D + (long)i * N_PTS;
#pragma unroll
    for (int s = 0; s < N_PTS / 256; s++) ds[t + 256 * s] = row[t + 256 * s];
    __syncthreads();
    for (int k = 0; k < KNN; k++) {
        float best = FLT_MAX;
        int bi = 0;
#pragma unroll
        for (int s = 0; s < N_PTS / 256; s++) {
            int j = t + 256 * s;
            float v = ds[j];
            if (v < best) { best = v; bi = j; }
        }
        rv[t] = best; ri[t] = bi;
        __syncthreads();
        for (int off = 128; off > 0; off >>= 1) {
            if (t < off && rv[t + off] < rv[t]) { rv[t] = rv[t + off]; ri[t] = ri[t + off]; }
            __syncthreads();
        }
        if (t == 0) {
            idxOut[i * KNN + k] = ri[0];
            ds[ri[0]] = FLT_MAX;
        }
        __syncthreads();
    }
}

// ---------------------------------------------------------------------------
// x (B,N,3) -> xt (B,3,N)
// ---------------------------------------------------------------------------
__global__ void prep_xt_kernel(const float* __restrict__ x, float* __restrict__ xt)
{
    int id = blockIdx.x * 256 + threadIdx.x;    // < 4*3*4096
    int b = id / (3 * N_PTS);
    int rem = id % (3 * N_PTS);
    int c = rem / N_PTS;
    int i = rem % N_PTS;
    xt[id] = x[((long)b * N_PTS + i) * 3 + c];
}

// ---------------------------------------------------------------------------
// xx[b][j] = sum_c F[b][c][j]^2
// ---------------------------------------------------------------------------
__global__ void sqnorm_kernel(const float* __restrict__ F, float* __restrict__ xx,
                              int C, long bsF)
{
    int b = blockIdx.y;
    int j = blockIdx.x * 256 + threadIdx.x;
    const float* f = F + (long)b * bsF;
    float s = 0.f;
    for (int c = 0; c < C; c++) {
        float t = f[(long)c * N_PTS + j];
        s = fmaf(t, t, s);
    }
    xx[(long)b * N_PTS + j] = s;
}

// ---------------------------------------------------------------------------
// Weight folding. Edge blocks: W (cout x 2C) -> Atq[c][o]=sc*Wd, Atp=sc*(Wc-Wd)
// ---------------------------------------------------------------------------
__global__ void fold_edge_kernel(const float* __restrict__ W, const float* __restrict__ g,
                                 const float* __restrict__ bb, const float* __restrict__ m,
                                 const float* __restrict__ v,
                                 float* __restrict__ Atq, float* __restrict__ Atp,
                                 float* __restrict__ shift, int C, int cout)
{
    int id = blockIdx.x * 256 + threadIdx.x;
    if (id < C * cout) {
        int o = id % cout;
        int c = id / cout;
        float sc = g[o] * rsqrtf(v[o] + EPSB);
        float wd = W[(long)o * 2 * C + c];
        float wc = W[(long)o * 2 * C + C + c];
        Atq[id] = sc * wd;             // id == c*cout + o
        Atp[id] = sc * (wc - wd);
    }
    if (id < cout) {
        float sc = g[id] * rsqrtf(v[id] + EPSB);
        shift[id] = bb[id] - m[id] * sc;
    }
}

__global__ void fold_plain_kernel(const float* __restrict__ W, const float* __restrict__ g,
                                  const float* __restrict__ bb, const float* __restrict__ m,
                                  const float* __restrict__ v,
                                  float* __restrict__ Atq, float* __restrict__ shift,
                                  int C, int cout)
{
    int id = blockIdx.x * 256 + threadIdx.x;
    if (id < C * cout) {
        int o = id % cout;
        int c = id / cout;
        float sc = g[o] * rsqrtf(v[o] + EPSB);
        Atq[id] = sc * W[(long)o * C + c];
    }
    if (id < cout) {
        float sc = g[id] * rsqrtf(v[id] + EPSB);
        shift[id] = bb[id] - m[id] * sc;
    }
}

// ---------------------------------------------------------------------------
// out[o,i] = max_k lrelu(q[idx[i,k]][o] + p[i][o]); write into cat slice
// grid (N/4, B), block (64,4)
// ---------------------------------------------------------------------------
__global__ void gather_max_kernel(const float* __restrict__ q, const float* __restrict__ p,
                                  const int* __restrict__ idx, float* __restrict__ cat,
                                  int cout, int c_off)
{
    int b = blockIdx.y;
    int i = blockIdx.x * 4 + threadIdx.y;
    int tx = threadIdx.x;
    const int* ip = idx + ((long)b * N_PTS + i) * KNN;
    int js[KNN];
#pragma unroll
    for (int k = 0; k < KNN; k++) js[k] = ip[k];
    const float* qb = q + (long)b * N_PTS * cout;
    const float* pb = p + ((long)b * N_PTS + i) * cout;
    float* ob = cat + ((long)b * 512 + c_off) * N_PTS + i;
    for (int o0 = 0; o0 < cout; o0 += 64) {
        int o = o0 + tx;
        float pv = pb[o];
        float mx = -FLT_MAX;
#pragma unroll
        for (int k = 0; k < KNN; k++) {
            float val = qb[(long)js[k] * cout + o] + pv;
            val = val >= 0.f ? val : 0.2f * val;
            mx = fmaxf(mx, val);
        }
        ob[(long)o * N_PTS] = mx;
    }
}

// ---------------------------------------------------------------------------
// Block 0: gf = [nb-c, cross(c,nb), c], W0 (64x9). grid (N/4,B), block (64,4)
// ---------------------------------------------------------------------------
__global__ void edge0_kernel(const float* __restrict__ xt, const int* __restrict__ idx,
                             const float* __restrict__ W0, const float* __restrict__ g0,
                             const float* __restrict__ b0, const float* __restrict__ m0,
                             const float* __restrict__ v0, float* __restrict__ cat)
{
    int b = blockIdx.y;
    int i = blockIdx.x * 4 + threadIdx.y;
    int o = threadIdx.x;
    const float* xb = xt + (long)b * 3 * N_PTS;
    float cx = xb[i], cy = xb[N_PTS + i], cz = xb[2 * N_PTS + i];
    float w[9];
#pragma unroll
    for (int c = 0; c < 9; c++) w[c] = W0[o * 9 + c];
    float sc = g0[o] * rsqrtf(v0[o] + EPSB);
    float sh = b0[o] - m0[o] * sc;
    const int* ip = idx + ((long)b * N_PTS + i) * KNN;
    float mx = -FLT_MAX;
#pragma unroll
    for (int k = 0; k < KNN; k++) {
        int j = ip[k];
        float nx = xb[j], ny = xb[N_PTS + j], nz = xb[2 * N_PTS + j];
        float dx = nx - cx, dy = ny - cy, dz = nz - cz;
        float crx = cy * nz - cz * ny;
        float cry = cz * nx - cx * nz;
        float crz = cx * ny - cy * nx;
        float y = w[0] * dx + w[1] * dy + w[2] * dz
                + w[3] * crx + w[4] * cry + w[5] * crz
                + w[6] * cx + w[7] * cy + w[8] * cz;
        y = y * sc + sh;
        y = y >= 0.f ? y : 0.2f * y;
        mx = fmaxf(mx, y);
    }
    cat[((long)b * 512 + o) * N_PTS + i] = mx;
}

// ---------------------------------------------------------------------------
// ymax[b][o] = max_i Y[b][o][i]; grid (512, B)
// ---------------------------------------------------------------------------
__global__ void rowmax_kernel(const float* __restrict__ Y, float* __restrict__ ymax)
{
    __shared__ float red[256];
    int b = blockIdx.y, o = blockIdx.x, t = threadIdx.x;
    const float* yb = Y + ((long)b * 512 + o) * N_PTS;
    float mx = -FLT_MAX;
#pragma unroll
    for (int s = 0; s < N_PTS / 256; s++) mx = fmaxf(mx, yb[t + 256 * s]);
    red[t] = mx;
    __syncthreads();
    for (int off = 128; off > 0; off >>= 1) {
        if (t < off) red[t] = fmaxf(red[t], red[t + off]);
        __syncthreads();
    }
    if (t == 0) ymax[(long)b * 512 + o] = red[0];
}

// ---------------------------------------------------------------------------
// emb = ymax @ We^T ; out = emb @ Wh^T + bh.  grid (B), block 128
// ---------------------------------------------------------------------------
__global__ void head_kernel(const float* __restrict__ ymax, const float* __restrict__ We,
                            const float* __restrict__ Wh, const float* __restrict__ bh,
                            float* __restrict__ out)
{
    __shared__ float emb[128];
    __shared__ float yv[512];
    int b = blockIdx.x, t = threadIdx.x;
    for (int s = t; s < 512; s += 128) yv[s] = ymax[(long)b * 512 + s];
    __syncthreads();
    float acc = 0.f;
    for (int c = 0; c < 512; c++) acc = fmaf(yv[c], We[(long)t * 512 + c], acc);
    emb[t] = acc;
    __syncthreads();
    float acc2 = bh[t];
    for (int ff = 0; ff < 128; ff++) acc2 = fmaf(emb[ff], Wh[(long)t * 128 + ff], acc2);
    out[(long)b * 128 + t] = acc2;
}

// ---------------------------------------------------------------------------
extern "C" void kernel_launch(void* const* d_in, const int* in_sizes, int n_in,
                              void* d_out, int out_size, void* d_ws, size_t ws_size,
                              hipStream_t stream)
{
    const float* x = (const float*)d_in[0];
    const float *W[5], *g[5], *bb[5], *m[5], *v[5];
    for (int li = 0; li < 5; li++) {
        W[li]  = (const float*)d_in[1 + li * 5 + 0];
        g[li]  = (const float*)d_in[1 + li * 5 + 1];
        bb[li] = (const float*)d_in[1 + li * 5 + 2];
        m[li]  = (const float*)d_in[1 + li * 5 + 3];
        v[li]  = (const float*)d_in[1 + li * 5 + 4];
    }
    const float* We = (const float*)d_in[26];
    const float* Wh = (const float*)d_in[27];
    const float* bh = (const float*)d_in[28];
    float* out = (float*)d_out;

    // workspace carve (floats). D region unioned with q/p (disjoint lifetimes).
    float* ws   = (float*)d_ws;
    float* Dbuf = ws;                                   // 16,777,216 (one batch NxN)
    float* qbuf = ws;                                   // <= 8,388,608
    float* pbuf = ws + (long)8388608;                   // <= 4,194,304 used
    float* cat  = ws + (long)16777216;                  // 8,388,608 (B,512,N)
    float* xt   = cat + (long)8388608;                  // 49,152
    float* xx   = xt + 49152;                           // 16,384
    int*   idxb = (int*)(xx + 16384);                   // 327,680 ints
    float* Atq  = (float*)(idxb + 327680);              // 262,144
    float* Atp  = Atq + 262144;                         // 262,144
    float* shf  = Atp + 262144;                         // 512
    float* ymax = shf + 512;                            // 2,048

    // ---- prep ----
    prep_xt_kernel<<<dim3(192), dim3(256), 0, stream>>>(x, xt);

    // ---- stage 0: knn on coords (C=3) ----
    sqnorm_kernel<<<dim3(16, NB), dim3(256), 0, stream>>>(xt, xx, 3, (long)3 * N_PTS);
    for (int b = 0; b < NB; b++) {
        const float* xb = xt + (long)b * 3 * N_PTS;
        gemm_kmajor<<<dim3(64, 64, 1), dim3(256), 0, stream>>>(
            xb, xb, Dbuf, xx + (long)b * N_PTS, xx + (long)b * N_PTS,
            3, N_PTS, N_PTS, N_PTS, 0, 0, 0, 3);
        topk_kernel<<<dim3(N_PTS), dim3(256), 0, stream>>>(Dbuf, idxb + (long)b * N_PTS * KNN);
    }
    edge0_kernel<<<dim3(N_PTS / 4, NB), dim3(64, 4), 0, stream>>>(
        xt, idxb, W[0], g[0], bb[0], m[0], v[0], cat);

    // ---- stages 1..3 ----
    const int Cs_[3]   = {64, 64, 128};
    const int co_[3]   = {64, 128, 256};
    const int inO_[3]  = {0, 64, 128};
    const int outO_[3] = {64, 128, 256};
    for (int s = 0; s < 3; s++) {
        int C = Cs_[s], cout = co_[s];
        const float* F = cat + (long)inO_[s] * N_PTS;   // batch stride 512*N
        sqnorm_kernel<<<dim3(16, NB), dim3(256), 0, stream>>>(F, xx, C, (long)512 * N_PTS);
        for (int b = 0; b < NB; b++) {
            const float* Fb = F + (long)b * 512 * N_PTS;
            gemm_kmajor<<<dim3(64, 64, 1), dim3(256), 0, stream>>>(
                Fb, Fb, Dbuf, xx + (long)b * N_PTS, xx + (long)b * N_PTS,
                C, N_PTS, N_PTS, N_PTS, 0, 0, 0, 3);
            topk_kernel<<<dim3(N_PTS), dim3(256), 0, stream>>>(Dbuf, idxb + (long)b * N_PTS * KNN);
        }
        int li = s + 1;
        fold_edge_kernel<<<dim3((C * cout + 255) / 256), dim3(256), 0, stream>>>(
            W[li], g[li], bb[li], m[li], v[li], Atq, Atp, shf, C, cout);
        // q: Out[j][o] point-major
        gemm_kmajor<<<dim3(N_PTS / 64, cout / 64, NB), dim3(256), 0, stream>>>(
            F, Atq, qbuf, nullptr, nullptr,
            C, N_PTS, cout, cout, (long)512 * N_PTS, 0, (long)N_PTS * cout, 0);
        // p: Out[i][o] + shift[o]
        gemm_kmajor<<<dim3(N_PTS / 64, cout / 64, NB), dim3(256), 0, stream>>>(
            F, Atp, pbuf, shf, nullptr,
            C, N_PTS, cout, cout, (long)512 * N_PTS, 0, (long)N_PTS * cout, 1);
        gather_max_kernel<<<dim3(N_PTS / 4, NB), dim3(64, 4), 0, stream>>>(
            qbuf, pbuf, idxb, cat, cout, outO_[s]);
    }

    // ---- stage 4: pointwise conv + bn + lrelu, channel-major out ----
    fold_plain_kernel<<<dim3((512 * 512 + 255) / 256), dim3(256), 0, stream>>>(
        W[4], g[4], bb[4], m[4], v[4], Atq, shf, 512, 512);
    gemm_kmajor<<<dim3(512 / 64, N_PTS / 64, NB), dim3(256), 0, stream>>>(
        Atq, cat, qbuf, shf, nullptr,
        512, 512, N_PTS, N_PTS, 0, (long)512 * N_PTS, (long)512 * N_PTS, 2);

    // ---- global max + head ----
    rowmax_kernel<<<dim3(512, NB), dim3(256), 0, stream>>>(qbuf, ymax);
    head_kernel<<<dim3(NB), dim3(128), 0, stream>>>(ymax, We, Wh, bh, out);
}

// Round 2
// 2153.562 us; speedup vs baseline: 1.0846x; 1.0846x over previous
//
#include <hip/hip_runtime.h>
#include <cfloat>

#define N_PTS 4096
#define NB    4
#define KNN   20
#define EPSB  1e-5f

#define BT 64
#define KT 16

// ---------------------------------------------------------------------------
// Generic K-major GEMM: Out[row][col] = sum_k Mr[k][row] * Mc[k][col]
// mode 0: plain  | mode 1: +aux1[col] | mode 2: lrelu(val+aux1[row])
// ---------------------------------------------------------------------------
__global__ __launch_bounds__(256)
void gemm_kmajor(const float* __restrict__ Mr, const float* __restrict__ Mc,
                 float* __restrict__ Out,
                 const float* __restrict__ aux1,
                 int K, int ldr, int ldc, int ldo,
                 long bsR, long bsC, long bsO,
                 int mode)
{
    __shared__ float Rs[KT][BT];
    __shared__ float Cs[KT][BT];
    int bz = blockIdx.z;
    const float* mr = Mr + bz * bsR;
    const float* mc = Mc + bz * bsC;
    float* outp = Out + bz * bsO;
    int row0 = blockIdx.x * BT;
    int col0 = blockIdx.y * BT;
    int tid = threadIdx.x;
    int tx = tid & 15, ty = tid >> 4;

    float acc[4][4];
#pragma unroll
    for (int r = 0; r < 4; r++)
#pragma unroll
        for (int c = 0; c < 4; c++) acc[r][c] = 0.f;

    for (int k0 = 0; k0 < K; k0 += KT) {
#pragma unroll
        for (int l = 0; l < (KT * BT) / 256; l++) {
            int e = l * 256 + tid;
            int kk = e >> 6, r = e & 63;
            int kg = k0 + kk;
            float rv = 0.f, cv = 0.f;
            if (kg < K) {
                rv = mr[(long)kg * ldr + row0 + r];
                cv = mc[(long)kg * ldc + col0 + r];
            }
            Rs[kk][r] = rv;
            Cs[kk][r] = cv;
        }
        __syncthreads();
#pragma unroll
        for (int kk = 0; kk < KT; kk++) {
            float rv[4], cv[4];
#pragma unroll
            for (int e = 0; e < 4; e++) rv[e] = Rs[kk][ty * 4 + e];
#pragma unroll
            for (int e = 0; e < 4; e++) cv[e] = Cs[kk][tx * 4 + e];
#pragma unroll
            for (int r = 0; r < 4; r++)
#pragma unroll
                for (int c = 0; c < 4; c++)
                    acc[r][c] = fmaf(rv[r], cv[c], acc[r][c]);
        }
        __syncthreads();
    }

    int orow = row0 + ty * 4;
    int ocol = col0 + tx * 4;
#pragma unroll
    for (int r = 0; r < 4; r++) {
        float vv[4];
#pragma unroll
        for (int c = 0; c < 4; c++) {
            float val = acc[r][c];
            if (mode == 1) {
                val += aux1[ocol + c];
            } else if (mode == 2) {
                val += aux1[orow + r];
                val = val >= 0.f ? val : 0.2f * val;
            }
            vv[c] = val;
        }
        float4 v4;
        v4.x = vv[0]; v4.y = vv[1]; v4.z = vv[2]; v4.w = vv[3];
        *(float4*)(outp + (long)(orow + r) * ldo + ocol) = v4;
    }
}

// ---------------------------------------------------------------------------
// Fused distance + top-20. Block: 64 queries x 2048 candidates (half).
// grid (N/64, 2, B), block 256.
// F: [b][KD][N] (row stride N_PTS, batch stride bsF), xx: [b][N]
// Out: knnd/knni [b][half][N][KNN] (sorted ascending)
// ---------------------------------------------------------------------------
template<int KD>
__global__ __launch_bounds__(256)
void fused_knn(const float* __restrict__ F, const float* __restrict__ xx,
               float* __restrict__ knnd, int* __restrict__ knni, long bsF)
{
    __shared__ float Qs[KD][64];
    __shared__ float Cs[KD][64];
    __shared__ float dtile[64][68];
    __shared__ int   stage_s[64][64];
    __shared__ float xxq_s[64];
    __shared__ float tau_s[64];
    __shared__ int   cnt_s[64];

    int b = blockIdx.z;
    int half = blockIdx.y;
    int q0 = blockIdx.x * 64;
    int c_base = half * 2048;
    const float* Fb = F + (long)b * bsF;
    const float* xxb = xx + (long)b * N_PTS;
    int tid = threadIdx.x;
    int tx = tid & 15, ty = tid >> 4;

    // preload query features + init select state
    for (int e = tid; e < KD * 16; e += 256) {
        int k = e >> 4, c4 = (e & 15) * 4;
        *(float4*)&Qs[k][c4] = *(const float4*)&Fb[(long)k * N_PTS + q0 + c4];
    }
    if (tid < 64) { xxq_s[tid] = xxb[q0 + tid]; tau_s[tid] = FLT_MAX; cnt_s[tid] = 0; }

    float d20[20]; int i20[20];
#pragma unroll
    for (int j = 0; j < KNN; j++) { d20[j] = FLT_MAX; i20[j] = 0; }

    constexpr int NLD = (KD * 16 + 255) / 256;

    __syncthreads();

    for (int t = 0; t < 2048 / 64; t++) {
        int cg0 = c_base + t * 64;
        // prefetch candidate tile into regs (overlaps prev tile's select phases)
        float4 creg[NLD];
#pragma unroll
        for (int i = 0; i < NLD; i++) {
            int e = tid + i * 256;
            if (e < KD * 16) {
                int k = e >> 4, c4 = (e & 15) * 4;
                creg[i] = *(const float4*)&Fb[(long)k * N_PTS + cg0 + c4];
            }
        }
        __syncthreads();   // prev tile fully consumed (dtile/stage/Cs free)
#pragma unroll
        for (int i = 0; i < NLD; i++) {
            int e = tid + i * 256;
            if (e < KD * 16) {
                int k = e >> 4, c4 = (e & 15) * 4;
                *(float4*)&Cs[k][c4] = creg[i];
            }
        }
        __syncthreads();   // Cs ready

        // phase A: 64x64 distance tile
        float acc[4][4];
#pragma unroll
        for (int r = 0; r < 4; r++)
#pragma unroll
            for (int c = 0; c < 4; c++) acc[r][c] = 0.f;
#pragma unroll 8
        for (int k = 0; k < KD; k++) {
            float4 cv = *(const float4*)&Cs[k][tx * 4];
            float4 qv = *(const float4*)&Qs[k][ty * 4];
            acc[0][0] = fmaf(qv.x, cv.x, acc[0][0]);
            acc[0][1] = fmaf(qv.x, cv.y, acc[0][1]);
            acc[0][2] = fmaf(qv.x, cv.z, acc[0][2]);
            acc[0][3] = fmaf(qv.x, cv.w, acc[0][3]);
            acc[1][0] = fmaf(qv.y, cv.x, acc[1][0]);
            acc[1][1] = fmaf(qv.y, cv.y, acc[1][1]);
            acc[1][2] = fmaf(qv.y, cv.z, acc[1][2]);
            acc[1][3] = fmaf(qv.y, cv.w, acc[1][3]);
            acc[2][0] = fmaf(qv.z, cv.x, acc[2][0]);
            acc[2][1] = fmaf(qv.z, cv.y, acc[2][1]);
            acc[2][2] = fmaf(qv.z, cv.z, acc[2][2]);
            acc[2][3] = fmaf(qv.z, cv.w, acc[2][3]);
            acc[3][0] = fmaf(qv.w, cv.x, acc[3][0]);
            acc[3][1] = fmaf(qv.w, cv.y, acc[3][1]);
            acc[3][2] = fmaf(qv.w, cv.z, acc[3][2]);
            acc[3][3] = fmaf(qv.w, cv.w, acc[3][3]);
        }
        float4 xc = *(const float4*)&xxb[cg0 + tx * 4];
#pragma unroll
        for (int r = 0; r < 4; r++) {
            float xq = xxq_s[ty * 4 + r];
            float4 dv;
            dv.x = xq + xc.x - 2.f * acc[r][0];
            dv.y = xq + xc.y - 2.f * acc[r][1];
            dv.z = xq + xc.z - 2.f * acc[r][2];
            dv.w = xq + xc.w - 2.f * acc[r][3];
            *(float4*)&dtile[ty * 4 + r][tx * 4] = dv;
        }
        __syncthreads();   // dtile ready

        // phase B1: tau-filter, stage survivors
        {
            int q = tid >> 2, s = tid & 3;
            float tau = tau_s[q];
#pragma unroll
            for (int j = 0; j < 16; j++) {
                int c = s * 16 + j;
                float d = dtile[q][c];
                if (d < tau) {
                    int pos = atomicAdd(&cnt_s[q], 1);
                    stage_s[q][pos] = c;
                }
            }
        }
        __syncthreads();   // staging done

        // phase B2: owners drain into register top-20
        if ((tid & 3) == 0) {
            int q = tid >> 2;
            int n = cnt_s[q];
            for (int mm = 0; mm < n; mm++) {
                int c = stage_s[q][mm];
                float d = dtile[q][c];
                if (d < d20[19]) {
                    int ci = cg0 + c;
#pragma unroll
                    for (int j = 19; j >= 1; j--) {
                        float pm = d20[j - 1]; int im = i20[j - 1];
                        bool sh  = d < pm;
                        bool ins = (!sh) && (d < d20[j]);
                        d20[j] = sh ? pm : (ins ? d  : d20[j]);
                        i20[j] = sh ? im : (ins ? ci : i20[j]);
                    }
                    if (d < d20[0]) { d20[0] = d; i20[0] = cg0 + c; }
                }
            }
            cnt_s[q] = 0;
            tau_s[q] = d20[19];
        }
        __syncthreads();   // close tile
    }

    if ((tid & 3) == 0) {
        int q = tid >> 2;
        long o = (((long)b * 2 + half) * N_PTS + (q0 + q)) * KNN;
#pragma unroll
        for (int j = 0; j < KNN; j++) { knnd[o + j] = d20[j]; knni[o + j] = i20[j]; }
    }
}

// ---------------------------------------------------------------------------
// Merge the two sorted half-lists per query into final idx[b][i][KNN]
// ---------------------------------------------------------------------------
__global__ void knn_merge(const float* __restrict__ knnd, const int* __restrict__ knni,
                          int* __restrict__ idxOut)
{
    int id = blockIdx.x * 256 + threadIdx.x;   // b*N + i
    int b = id / N_PTS, i = id % N_PTS;
    const float* da = knnd + (((long)b * 2 + 0) * N_PTS + i) * KNN;
    const float* db = knnd + (((long)b * 2 + 1) * N_PTS + i) * KNN;
    const int*   ia = knni + (((long)b * 2 + 0) * N_PTS + i) * KNN;
    const int*   ib = knni + (((long)b * 2 + 1) * N_PTS + i) * KNN;
    int* o = idxOut + (long)id * KNN;
    int pa = 0, pb = 0;
#pragma unroll
    for (int j = 0; j < KNN; j++) {
        float va = da[pa], vb = db[pb];
        if (va <= vb) o[j] = ia[pa++];
        else          o[j] = ib[pb++];
    }
}

// ---------------------------------------------------------------------------
__global__ void prep_xt_kernel(const float* __restrict__ x, float* __restrict__ xt)
{
    int id = blockIdx.x * 256 + threadIdx.x;    // < 4*3*4096
    int b = id / (3 * N_PTS);
    int rem = id % (3 * N_PTS);
    int c = rem / N_PTS;
    int i = rem % N_PTS;
    xt[id] = x[((long)b * N_PTS + i) * 3 + c];
}

__global__ void sqnorm_kernel(const float* __restrict__ F, float* __restrict__ xx,
                              int C, long bsF)
{
    int b = blockIdx.y;
    int j = blockIdx.x * 256 + threadIdx.x;
    const float* f = F + (long)b * bsF;
    float s = 0.f;
    for (int c = 0; c < C; c++) {
        float t = f[(long)c * N_PTS + j];
        s = fmaf(t, t, s);
    }
    xx[(long)b * N_PTS + j] = s;
}

__global__ void fold_edge_kernel(const float* __restrict__ W, const float* __restrict__ g,
                                 const float* __restrict__ bb, const float* __restrict__ m,
                                 const float* __restrict__ v,
                                 float* __restrict__ Atq, float* __restrict__ Atp,
                                 float* __restrict__ shift, int C, int cout)
{
    int id = blockIdx.x * 256 + threadIdx.x;
    if (id < C * cout) {
        int o = id % cout;
        int c = id / cout;
        float sc = g[o] * rsqrtf(v[o] + EPSB);
        float wd = W[(long)o * 2 * C + c];
        float wc = W[(long)o * 2 * C + C + c];
        Atq[id] = sc * wd;
        Atp[id] = sc * (wc - wd);
    }
    if (id < cout) {
        float sc = g[id] * rsqrtf(v[id] + EPSB);
        shift[id] = bb[id] - m[id] * sc;
    }
}

__global__ void fold_plain_kernel(const float* __restrict__ W, const float* __restrict__ g,
                                  const float* __restrict__ bb, const float* __restrict__ m,
                                  const float* __restrict__ v,
                                  float* __restrict__ Atq, float* __restrict__ shift,
                                  int C, int cout)
{
    int id = blockIdx.x * 256 + threadIdx.x;
    if (id < C * cout) {
        int o = id % cout;
        int c = id / cout;
        float sc = g[o] * rsqrtf(v[o] + EPSB);
        Atq[id] = sc * W[(long)o * C + c];
    }
    if (id < cout) {
        float sc = g[id] * rsqrtf(v[id] + EPSB);
        shift[id] = bb[id] - m[id] * sc;
    }
}

__global__ void gather_max_kernel(const float* __restrict__ q, const float* __restrict__ p,
                                  const int* __restrict__ idx, float* __restrict__ cat,
                                  int cout, int c_off)
{
    int b = blockIdx.y;
    int i = blockIdx.x * 4 + threadIdx.y;
    int tx = threadIdx.x;
    const int* ip = idx + ((long)b * N_PTS + i) * KNN;
    int js[KNN];
#pragma unroll
    for (int k = 0; k < KNN; k++) js[k] = ip[k];
    const float* qb = q + (long)b * N_PTS * cout;
    const float* pb = p + ((long)b * N_PTS + i) * cout;
    float* ob = cat + ((long)b * 512 + c_off) * N_PTS + i;
    for (int o0 = 0; o0 < cout; o0 += 64) {
        int o = o0 + tx;
        float pv = pb[o];
        float mx = -FLT_MAX;
#pragma unroll
        for (int k = 0; k < KNN; k++) {
            float val = qb[(long)js[k] * cout + o] + pv;
            val = val >= 0.f ? val : 0.2f * val;
            mx = fmaxf(mx, val);
        }
        ob[(long)o * N_PTS] = mx;
    }
}

__global__ void edge0_kernel(const float* __restrict__ xt, const int* __restrict__ idx,
                             const float* __restrict__ W0, const float* __restrict__ g0,
                             const float* __restrict__ b0, const float* __restrict__ m0,
                             const float* __restrict__ v0, float* __restrict__ cat)
{
    int b = blockIdx.y;
    int i = blockIdx.x * 4 + threadIdx.y;
    int o = threadIdx.x;
    const float* xb = xt + (long)b * 3 * N_PTS;
    float cx = xb[i], cy = xb[N_PTS + i], cz = xb[2 * N_PTS + i];
    float w[9];
#pragma unroll
    for (int c = 0; c < 9; c++) w[c] = W0[o * 9 + c];
    float sc = g0[o] * rsqrtf(v0[o] + EPSB);
    float sh = b0[o] - m0[o] * sc;
    const int* ip = idx + ((long)b * N_PTS + i) * KNN;
    float mx = -FLT_MAX;
#pragma unroll
    for (int k = 0; k < KNN; k++) {
        int j = ip[k];
        float nx = xb[j], ny = xb[N_PTS + j], nz = xb[2 * N_PTS + j];
        float dx = nx - cx, dy = ny - cy, dz = nz - cz;
        float crx = cy * nz - cz * ny;
        float cry = cz * nx - cx * nz;
        float crz = cx * ny - cy * nx;
        float y = w[0] * dx + w[1] * dy + w[2] * dz
                + w[3] * crx + w[4] * cry + w[5] * crz
                + w[6] * cx + w[7] * cy + w[8] * cz;
        y = y * sc + sh;
        y = y >= 0.f ? y : 0.2f * y;
        mx = fmaxf(mx, y);
    }
    cat[((long)b * 512 + o) * N_PTS + i] = mx;
}

__global__ void rowmax_kernel(const float* __restrict__ Y, float* __restrict__ ymax)
{
    __shared__ float red[256];
    int b = blockIdx.y, o = blockIdx.x, t = threadIdx.x;
    const float* yb = Y + ((long)b * 512 + o) * N_PTS;
    float mx = -FLT_MAX;
#pragma unroll
    for (int s = 0; s < N_PTS / 256; s++) mx = fmaxf(mx, yb[t + 256 * s]);
    red[t] = mx;
    __syncthreads();
    for (int off = 128; off > 0; off >>= 1) {
        if (t < off) red[t] = fmaxf(red[t], red[t + off]);
        __syncthreads();
    }
    if (t == 0) ymax[(long)b * 512 + o] = red[0];
}

__global__ void head_kernel(const float* __restrict__ ymax, const float* __restrict__ We,
                            const float* __restrict__ Wh, const float* __restrict__ bh,
                            float* __restrict__ out)
{
    __shared__ float emb[128];
    __shared__ float yv[512];
    int b = blockIdx.x, t = threadIdx.x;
    for (int s = t; s < 512; s += 128) yv[s] = ymax[(long)b * 512 + s];
    __syncthreads();
    float acc = 0.f;
    for (int c = 0; c < 512; c++) acc = fmaf(yv[c], We[(long)t * 512 + c], acc);
    emb[t] = acc;
    __syncthreads();
    float acc2 = bh[t];
    for (int ff = 0; ff < 128; ff++) acc2 = fmaf(emb[ff], Wh[(long)t * 128 + ff], acc2);
    out[(long)b * 128 + t] = acc2;
}

// ---------------------------------------------------------------------------
extern "C" void kernel_launch(void* const* d_in, const int* in_sizes, int n_in,
                              void* d_out, int out_size, void* d_ws, size_t ws_size,
                              hipStream_t stream)
{
    const float* x = (const float*)d_in[0];
    const float *W[5], *g[5], *bb[5], *m[5], *v[5];
    for (int li = 0; li < 5; li++) {
        W[li]  = (const float*)d_in[1 + li * 5 + 0];
        g[li]  = (const float*)d_in[1 + li * 5 + 1];
        bb[li] = (const float*)d_in[1 + li * 5 + 2];
        m[li]  = (const float*)d_in[1 + li * 5 + 3];
        v[li]  = (const float*)d_in[1 + li * 5 + 4];
    }
    const float* We = (const float*)d_in[26];
    const float* Wh = (const float*)d_in[27];
    const float* bh = (const float*)d_in[28];
    float* out = (float*)d_out;

    // workspace carve (floats)
    float* ws   = (float*)d_ws;
    float* cat  = ws;                                   // 8,388,608 (B,512,N)
    float* qbuf = cat + (long)8388608;                  // 8,388,608 (q + stage4 Y)
    float* pbuf = qbuf + (long)8388608;                 // 4,194,304
    float* knnd = pbuf + (long)4194304;                 // 655,360
    int*   knni = (int*)(knnd + 655360);                // 655,360
    int*   idxb = knni + 655360;                        // 327,680
    float* xt   = (float*)(idxb + 327680);              // 49,152
    float* xx   = xt + 49152;                           // 16,384
    float* Atq  = xx + 16384;                           // 262,144
    float* Atp  = Atq + 262144;                         // 262,144
    float* shf  = Atp + 262144;                         // 512
    float* ymax = shf + 512;                            // 2,048

    // ---- prep ----
    prep_xt_kernel<<<dim3(192), dim3(256), 0, stream>>>(x, xt);

    // ---- stage 0: knn on coords (C=3) ----
    sqnorm_kernel<<<dim3(16, NB), dim3(256), 0, stream>>>(xt, xx, 3, (long)3 * N_PTS);
    fused_knn<3><<<dim3(N_PTS / 64, 2, NB), dim3(256), 0, stream>>>(
        xt, xx, knnd, knni, (long)3 * N_PTS);
    knn_merge<<<dim3(64), dim3(256), 0, stream>>>(knnd, knni, idxb);
    edge0_kernel<<<dim3(N_PTS / 4, NB), dim3(64, 4), 0, stream>>>(
        xt, idxb, W[0], g[0], bb[0], m[0], v[0], cat);

    // ---- stages 1..3 ----
    const int Cs_[3]   = {64, 64, 128};
    const int co_[3]   = {64, 128, 256};
    const int inO_[3]  = {0, 64, 128};
    const int outO_[3] = {64, 128, 256};
    for (int s = 0; s < 3; s++) {
        int C = Cs_[s], cout = co_[s];
        const float* F = cat + (long)inO_[s] * N_PTS;   // batch stride 512*N
        sqnorm_kernel<<<dim3(16, NB), dim3(256), 0, stream>>>(F, xx, C, (long)512 * N_PTS);
        if (C == 64)
            fused_knn<64><<<dim3(N_PTS / 64, 2, NB), dim3(256), 0, stream>>>(
                F, xx, knnd, knni, (long)512 * N_PTS);
        else
            fused_knn<128><<<dim3(N_PTS / 64, 2, NB), dim3(256), 0, stream>>>(
                F, xx, knnd, knni, (long)512 * N_PTS);
        knn_merge<<<dim3(64), dim3(256), 0, stream>>>(knnd, knni, idxb);

        int li = s + 1;
        fold_edge_kernel<<<dim3((C * cout + 255) / 256), dim3(256), 0, stream>>>(
            W[li], g[li], bb[li], m[li], v[li], Atq, Atp, shf, C, cout);
        // q: Out[j][o] point-major
        gemm_kmajor<<<dim3(N_PTS / 64, cout / 64, NB), dim3(256), 0, stream>>>(
            F, Atq, qbuf, nullptr,
            C, N_PTS, cout, cout, (long)512 * N_PTS, 0, (long)N_PTS * cout, 0);
        // p: Out[i][o] + shift[o]
        gemm_kmajor<<<dim3(N_PTS / 64, cout / 64, NB), dim3(256), 0, stream>>>(
            F, Atp, pbuf, shf,
            C, N_PTS, cout, cout, (long)512 * N_PTS, 0, (long)N_PTS * cout, 1);
        gather_max_kernel<<<dim3(N_PTS / 4, NB), dim3(64, 4), 0, stream>>>(
            qbuf, pbuf, idxb, cat, cout, outO_[s]);
    }

    // ---- stage 4: pointwise conv + bn + lrelu, channel-major out ----
    fold_plain_kernel<<<dim3((512 * 512 + 255) / 256), dim3(256), 0, stream>>>(
        W[4], g[4], bb[4], m[4], v[4], Atq, shf, 512, 512);
    gemm_kmajor<<<dim3(512 / 64, N_PTS / 64, NB), dim3(256), 0, stream>>>(
        Atq, cat, qbuf, shf,
        512, 512, N_PTS, N_PTS, 0, (long)512 * N_PTS, (long)512 * N_PTS, 2);

    // ---- global max + head ----
    rowmax_kernel<<<dim3(512, NB), dim3(256), 0, stream>>>(qbuf, ymax);
    head_kernel<<<dim3(NB), dim3(128), 0, stream>>>(ymax, We, Wh, bh, out);
}

// Round 3
// 2055.871 us; speedup vs baseline: 1.1362x; 1.0475x over previous
//
#include <hip/hip_runtime.h>
#include <cfloat>

#define N_PTS 4096
#define NB    4
#define KNN   20
#define EPSB  1e-5f

#define BT 64
#define KT 16

// ---------------------------------------------------------------------------
// Generic K-major GEMM: Out[row][col] = sum_k Mr[k][row] * Mc[k][col]
// mode 0: plain  | mode 1: +aux1[col] | mode 2: lrelu(val+aux1[row])
// ---------------------------------------------------------------------------
__global__ __launch_bounds__(256)
void gemm_kmajor(const float* __restrict__ Mr, const float* __restrict__ Mc,
                 float* __restrict__ Out,
                 const float* __restrict__ aux1,
                 int K, int ldr, int ldc, int ldo,
                 long bsR, long bsC, long bsO,
                 int mode)
{
    __shared__ float Rs[KT][BT];
    __shared__ float Cs[KT][BT];
    int bz = blockIdx.z;
    const float* mr = Mr + bz * bsR;
    const float* mc = Mc + bz * bsC;
    float* outp = Out + bz * bsO;
    int row0 = blockIdx.x * BT;
    int col0 = blockIdx.y * BT;
    int tid = threadIdx.x;
    int tx = tid & 15, ty = tid >> 4;

    float acc[4][4];
#pragma unroll
    for (int r = 0; r < 4; r++)
#pragma unroll
        for (int c = 0; c < 4; c++) acc[r][c] = 0.f;

    for (int k0 = 0; k0 < K; k0 += KT) {
#pragma unroll
        for (int l = 0; l < (KT * BT) / 256; l++) {
            int e = l * 256 + tid;
            int kk = e >> 6, r = e & 63;
            int kg = k0 + kk;
            float rv = 0.f, cv = 0.f;
            if (kg < K) {
                rv = mr[(long)kg * ldr + row0 + r];
                cv = mc[(long)kg * ldc + col0 + r];
            }
            Rs[kk][r] = rv;
            Cs[kk][r] = cv;
        }
        __syncthreads();
#pragma unroll
        for (int kk = 0; kk < KT; kk++) {
            float rv[4], cv[4];
#pragma unroll
            for (int e = 0; e < 4; e++) rv[e] = Rs[kk][ty * 4 + e];
#pragma unroll
            for (int e = 0; e < 4; e++) cv[e] = Cs[kk][tx * 4 + e];
#pragma unroll
            for (int r = 0; r < 4; r++)
#pragma unroll
                for (int c = 0; c < 4; c++)
                    acc[r][c] = fmaf(rv[r], cv[c], acc[r][c]);
        }
        __syncthreads();
    }

    int orow = row0 + ty * 4;
    int ocol = col0 + tx * 4;
#pragma unroll
    for (int r = 0; r < 4; r++) {
        float vv[4];
#pragma unroll
        for (int c = 0; c < 4; c++) {
            float val = acc[r][c];
            if (mode == 1) {
                val += aux1[ocol + c];
            } else if (mode == 2) {
                val += aux1[orow + r];
                val = val >= 0.f ? val : 0.2f * val;
            }
            vv[c] = val;
        }
        float4 v4;
        v4.x = vv[0]; v4.y = vv[1]; v4.z = vv[2]; v4.w = vv[3];
        *(float4*)(outp + (long)(orow + r) * ldo + ocol) = v4;
    }
}

// ---------------------------------------------------------------------------
// Wave-synchronous fused distance + top-20.
// grid (N/64, 4 quarters, B), block 256 (4 waves).
// Block: 64 queries x 1024 candidates. Each wave independently handles 256
// candidates (4 tiles of 64) for all 64 queries: 8x8 frag per lane.
// Lane L: qg=L>>3 -> rows q=(L&56)+r; cg=L&7 -> cols c=cg*8+j.
// Lane L is owner of query q==L (register top-20). No __syncthreads in the
// main loop; no LDS atomics; all LDS patterns <=2-way banked.
// Out: knnd/knni [b][quart][N][KNN] sorted ascending.
// ---------------------------------------------------------------------------
template<int KD>
__global__ __launch_bounds__(256)
void fused_knn2(const float* __restrict__ F, const float* __restrict__ xx,
                float* __restrict__ knnd, int* __restrict__ knni, long bsF)
{
    constexpr int CH = (KD < 16) ? KD : 16;            // k-chunk
    constexpr int MAIN = KD * 256 + 4 * CH * 256 + 4 * 64 * 17 * 4;
    constexpr int SMEM = MAIN > 40964 ? MAIN : 40964;  // merge scratch needs 40960
    __shared__ __align__(16) char smem[SMEM];

    int tid = threadIdx.x;
    int w = tid >> 6;
    int L = tid & 63;
    int qg8 = L & 56;          // q-base of this lane's rows
    int cg = L & 7;

    float* Qs  = (float*)smem;                                     // [KD][64]
    float* Csw = (float*)(smem + KD * 256) + w * CH * 64;          // [CH][64]
    float* dtw = (float*)(smem + KD * 256 + 4 * CH * 256) + w * 64 * 17;

    int b = blockIdx.z;
    int quart = blockIdx.y;
    int q0 = blockIdx.x * 64;
    const float* Fb = F + (long)b * bsF;
    const float* xxb = xx + (long)b * N_PTS;

    // cooperative Q load (one barrier total)
    for (int e = tid; e < KD * 64; e += 256) {
        int k = e >> 6, q = e & 63;
        Qs[k * 64 + q] = Fb[(long)k * N_PTS + q0 + q];
    }
    float xqf[8];
    *(float4*)&xqf[0] = *(const float4*)&xxb[q0 + qg8];
    *(float4*)&xqf[4] = *(const float4*)&xxb[q0 + qg8 + 4];

    float d20[KNN]; int i20[KNN];
#pragma unroll
    for (int j = 0; j < KNN; j++) { d20[j] = FLT_MAX; i20[j] = 0; }

    __syncthreads();

    int cwave = quart * 1024 + w * 256;
    for (int t = 0; t < 4; t++) {
        int c0 = cwave + t * 64;
        float acc[8][8];
#pragma unroll
        for (int r = 0; r < 8; r++)
#pragma unroll
            for (int j = 0; j < 8; j++) acc[r][j] = 0.f;

        for (int k0 = 0; k0 < KD; k0 += CH) {
            // wave-private candidate chunk staging (no barrier)
            for (int e = L; e < CH * 64; e += 64) {
                int kk = e >> 6, c = e & 63;
                Csw[kk * 64 + c] = Fb[(long)(k0 + kk) * N_PTS + c0 + c];
            }
#pragma unroll
            for (int kk = 0; kk < CH; kk++) {
                float qf[8], cf[8];
                *(float4*)&qf[0] = *(const float4*)&Qs[(k0 + kk) * 64 + qg8];
                *(float4*)&qf[4] = *(const float4*)&Qs[(k0 + kk) * 64 + qg8 + 4];
                *(float4*)&cf[0] = *(const float4*)&Csw[kk * 64 + cg * 8];
                *(float4*)&cf[4] = *(const float4*)&Csw[kk * 64 + cg * 8 + 4];
#pragma unroll
                for (int r = 0; r < 8; r++)
#pragma unroll
                    for (int j = 0; j < 8; j++)
                        acc[r][j] = fmaf(qf[r], cf[j], acc[r][j]);
            }
        }

        // distances in-place
        float xcf[8];
        *(float4*)&xcf[0] = *(const float4*)&xxb[c0 + cg * 8];
        *(float4*)&xcf[4] = *(const float4*)&xxb[c0 + cg * 8 + 4];
#pragma unroll
        for (int r = 0; r < 8; r++)
#pragma unroll
            for (int j = 0; j < 8; j++)
                acc[r][j] = xqf[r] + xcf[j] - 2.f * acc[r][j];

        // selection: 4 slabs of 16 candidates (j = 2*s4 + jj)
#pragma unroll
        for (int s4 = 0; s4 < 4; s4++) {
            float tau[8];
#pragma unroll
            for (int r = 0; r < 8; r++) tau[r] = __shfl(d20[KNN - 1], qg8 + r);

            // write slab to per-wave dtile: row q, col jj*8+cg (2-way banked)
#pragma unroll
            for (int r = 0; r < 8; r++) {
                dtw[(qg8 + r) * 17 + cg]     = acc[r][s4 * 2];
                dtw[(qg8 + r) * 17 + 8 + cg] = acc[r][s4 * 2 + 1];
            }

            // ballot-based survivor bitmap (bit p = jj*8 + src_cg)
            unsigned bm = 0;
#pragma unroll
            for (int jj = 0; jj < 2; jj++)
#pragma unroll
                for (int r = 0; r < 8; r++) {
                    unsigned long long bal =
                        __ballot(acc[r][s4 * 2 + jj] < tau[r]);
                    if ((L & 7) == r)
                        bm |= (unsigned)((bal >> qg8) & 255ull) << (8 * jj);
                }

            // owner drain: lane L owns query q0+L; dtile col index == bit p
            while (bm) {
                int p = __builtin_ctz(bm);
                bm &= bm - 1;
                float dv = dtw[L * 17 + p];
                if (dv < d20[KNN - 1]) {
                    int ci = c0 + (p & 7) * 8 + s4 * 2 + (p >> 3);
#pragma unroll
                    for (int j2 = KNN - 1; j2 >= 1; j2--) {
                        float pm = d20[j2 - 1]; int im = i20[j2 - 1];
                        bool sh  = dv < pm;
                        bool ins = (!sh) && (dv < d20[j2]);
                        d20[j2] = sh ? pm : (ins ? dv : d20[j2]);
                        i20[j2] = sh ? im : (ins ? ci : i20[j2]);
                    }
                    if (dv < d20[0]) { d20[0] = dv; i20[0] = ci; }
                }
            }
        }
    }

    // block merge: 4 wave-lists per query -> one sorted 20-list
    __syncthreads();
    float* md = (float*)smem;                       // [4][64][20]
    int*   mi = (int*)(smem + 4 * 64 * KNN * 4);    // [4][64][20]
#pragma unroll
    for (int j = 0; j < KNN; j++) {
        md[(w * 64 + L) * KNN + j] = d20[j];
        mi[(w * 64 + L) * KNN + j] = i20[j];
    }
    __syncthreads();
    if (tid < 64) {
        int q = tid;
        int p[4] = {0, 0, 0, 0};
        long o = (((long)b * 4 + quart) * N_PTS + (q0 + q)) * KNN;
        for (int j = 0; j < KNN; j++) {
            float best = FLT_MAX; int bw = 0;
#pragma unroll
            for (int wv = 0; wv < 4; wv++) {
                float vv = md[(wv * 64 + q) * KNN + p[wv]];
                if (vv < best) { best = vv; bw = wv; }
            }
            knnd[o + j] = best;
            knni[o + j] = mi[(bw * 64 + q) * KNN + p[bw]];
            p[bw]++;
        }
    }
}

// ---------------------------------------------------------------------------
// Merge the four sorted quarter-lists per query into final idx[b][i][KNN]
// (set semantics — downstream max-pool is order-invariant)
// ---------------------------------------------------------------------------
__global__ void knn_merge4(const float* __restrict__ knnd, const int* __restrict__ knni,
                           int* __restrict__ idxOut)
{
    int id = blockIdx.x * 256 + threadIdx.x;   // b*N + i
    int b = id / N_PTS, i = id % N_PTS;
    const float* dl[4]; const int* il[4];
#pragma unroll
    for (int qt = 0; qt < 4; qt++) {
        dl[qt] = knnd + (((long)b * 4 + qt) * N_PTS + i) * KNN;
        il[qt] = knni + (((long)b * 4 + qt) * N_PTS + i) * KNN;
    }
    int p[4] = {0, 0, 0, 0};
    int* o = idxOut + (long)id * KNN;
#pragma unroll
    for (int j = 0; j < KNN; j++) {
        float best = FLT_MAX; int bq = 0;
#pragma unroll
        for (int qt = 0; qt < 4; qt++) {
            float vv = (p[qt] < KNN) ? dl[qt][p[qt]] : FLT_MAX;
            if (vv < best) { best = vv; bq = qt; }
        }
        o[j] = il[bq][p[bq]];
        p[bq]++;
    }
}

// ---------------------------------------------------------------------------
__global__ void prep_xt_kernel(const float* __restrict__ x, float* __restrict__ xt)
{
    int id = blockIdx.x * 256 + threadIdx.x;    // < 4*3*4096
    int b = id / (3 * N_PTS);
    int rem = id % (3 * N_PTS);
    int c = rem / N_PTS;
    int i = rem % N_PTS;
    xt[id] = x[((long)b * N_PTS + i) * 3 + c];
}

__global__ void sqnorm_kernel(const float* __restrict__ F, float* __restrict__ xx,
                              int C, long bsF)
{
    int b = blockIdx.y;
    int j = blockIdx.x * 256 + threadIdx.x;
    const float* f = F + (long)b * bsF;
    float s = 0.f;
    for (int c = 0; c < C; c++) {
        float t = f[(long)c * N_PTS + j];
        s = fmaf(t, t, s);
    }
    xx[(long)b * N_PTS + j] = s;
}

__global__ void fold_edge_kernel(const float* __restrict__ W, const float* __restrict__ g,
                                 const float* __restrict__ bb, const float* __restrict__ m,
                                 const float* __restrict__ v,
                                 float* __restrict__ Atq, float* __restrict__ Atp,
                                 float* __restrict__ shift, int C, int cout)
{
    int id = blockIdx.x * 256 + threadIdx.x;
    if (id < C * cout) {
        int o = id % cout;
        int c = id / cout;
        float sc = g[o] * rsqrtf(v[o] + EPSB);
        float wd = W[(long)o * 2 * C + c];
        float wc = W[(long)o * 2 * C + C + c];
        Atq[id] = sc * wd;
        Atp[id] = sc * (wc - wd);
    }
    if (id < cout) {
        float sc = g[id] * rsqrtf(v[id] + EPSB);
        shift[id] = bb[id] - m[id] * sc;
    }
}

__global__ void fold_plain_kernel(const float* __restrict__ W, const float* __restrict__ g,
                                  const float* __restrict__ bb, const float* __restrict__ m,
                                  const float* __restrict__ v,
                                  float* __restrict__ Atq, float* __restrict__ shift,
                                  int C, int cout)
{
    int id = blockIdx.x * 256 + threadIdx.x;
    if (id < C * cout) {
        int o = id % cout;
        int c = id / cout;
        float sc = g[o] * rsqrtf(v[o] + EPSB);
        Atq[id] = sc * W[(long)o * C + c];
    }
    if (id < cout) {
        float sc = g[id] * rsqrtf(v[id] + EPSB);
        shift[id] = bb[id] - m[id] * sc;
    }
}

__global__ void gather_max_kernel(const float* __restrict__ q, const float* __restrict__ p,
                                  const int* __restrict__ idx, float* __restrict__ cat,
                                  int cout, int c_off)
{
    int b = blockIdx.y;
    int i = blockIdx.x * 4 + threadIdx.y;
    int tx = threadIdx.x;
    const int* ip = idx + ((long)b * N_PTS + i) * KNN;
    int js[KNN];
#pragma unroll
    for (int k = 0; k < KNN; k++) js[k] = ip[k];
    const float* qb = q + (long)b * N_PTS * cout;
    const float* pb = p + ((long)b * N_PTS + i) * cout;
    float* ob = cat + ((long)b * 512 + c_off) * N_PTS + i;
    for (int o0 = 0; o0 < cout; o0 += 64) {
        int o = o0 + tx;
        float pv = pb[o];
        float mx = -FLT_MAX;
#pragma unroll
        for (int k = 0; k < KNN; k++) {
            float val = qb[(long)js[k] * cout + o] + pv;
            val = val >= 0.f ? val : 0.2f * val;
            mx = fmaxf(mx, val);
        }
        ob[(long)o * N_PTS] = mx;
    }
}

__global__ void edge0_kernel(const float* __restrict__ xt, const int* __restrict__ idx,
                             const float* __restrict__ W0, const float* __restrict__ g0,
                             const float* __restrict__ b0, const float* __restrict__ m0,
                             const float* __restrict__ v0, float* __restrict__ cat)
{
    int b = blockIdx.y;
    int i = blockIdx.x * 4 + threadIdx.y;
    int o = threadIdx.x;
    const float* xb = xt + (long)b * 3 * N_PTS;
    float cx = xb[i], cy = xb[N_PTS + i], cz = xb[2 * N_PTS + i];
    float w[9];
#pragma unroll
    for (int c = 0; c < 9; c++) w[c] = W0[o * 9 + c];
    float sc = g0[o] * rsqrtf(v0[o] + EPSB);
    float sh = b0[o] - m0[o] * sc;
    const int* ip = idx + ((long)b * N_PTS + i) * KNN;
    float mx = -FLT_MAX;
#pragma unroll
    for (int k = 0; k < KNN; k++) {
        int j = ip[k];
        float nx = xb[j], ny = xb[N_PTS + j], nz = xb[2 * N_PTS + j];
        float dx = nx - cx, dy = ny - cy, dz = nz - cz;
        float crx = cy * nz - cz * ny;
        float cry = cz * nx - cx * nz;
        float crz = cx * ny - cy * nx;
        float y = w[0] * dx + w[1] * dy + w[2] * dz
                + w[3] * crx + w[4] * cry + w[5] * crz
                + w[6] * cx + w[7] * cy + w[8] * cz;
        y = y * sc + sh;
        y = y >= 0.f ? y : 0.2f * y;
        mx = fmaxf(mx, y);
    }
    cat[((long)b * 512 + o) * N_PTS + i] = mx;
}

__global__ void rowmax_kernel(const float* __restrict__ Y, float* __restrict__ ymax)
{
    __shared__ float red[256];
    int b = blockIdx.y, o = blockIdx.x, t = threadIdx.x;
    const float* yb = Y + ((long)b * 512 + o) * N_PTS;
    float mx = -FLT_MAX;
#pragma unroll
    for (int s = 0; s < N_PTS / 256; s++) mx = fmaxf(mx, yb[t + 256 * s]);
    red[t] = mx;
    __syncthreads();
    for (int off = 128; off > 0; off >>= 1) {
        if (t < off) red[t] = fmaxf(red[t], red[t + off]);
        __syncthreads();
    }
    if (t == 0) ymax[(long)b * 512 + o] = red[0];
}

__global__ void head_kernel(const float* __restrict__ ymax, const float* __restrict__ We,
                            const float* __restrict__ Wh, const float* __restrict__ bh,
                            float* __restrict__ out)
{
    __shared__ float emb[128];
    __shared__ float yv[512];
    int b = blockIdx.x, t = threadIdx.x;
    for (int s = t; s < 512; s += 128) yv[s] = ymax[(long)b * 512 + s];
    __syncthreads();
    float acc = 0.f;
    for (int c = 0; c < 512; c++) acc = fmaf(yv[c], We[(long)t * 512 + c], acc);
    emb[t] = acc;
    __syncthreads();
    float acc2 = bh[t];
    for (int ff = 0; ff < 128; ff++) acc2 = fmaf(emb[ff], Wh[(long)t * 128 + ff], acc2);
    out[(long)b * 128 + t] = acc2;
}

// ---------------------------------------------------------------------------
extern "C" void kernel_launch(void* const* d_in, const int* in_sizes, int n_in,
                              void* d_out, int out_size, void* d_ws, size_t ws_size,
                              hipStream_t stream)
{
    const float* x = (const float*)d_in[0];
    const float *W[5], *g[5], *bb[5], *m[5], *v[5];
    for (int li = 0; li < 5; li++) {
        W[li]  = (const float*)d_in[1 + li * 5 + 0];
        g[li]  = (const float*)d_in[1 + li * 5 + 1];
        bb[li] = (const float*)d_in[1 + li * 5 + 2];
        m[li]  = (const float*)d_in[1 + li * 5 + 3];
        v[li]  = (const float*)d_in[1 + li * 5 + 4];
    }
    const float* We = (const float*)d_in[26];
    const float* Wh = (const float*)d_in[27];
    const float* bh = (const float*)d_in[28];
    float* out = (float*)d_out;

    // workspace carve (floats)
    float* ws   = (float*)d_ws;
    float* cat  = ws;                                   // 8,388,608 (B,512,N)
    float* qbuf = cat + (long)8388608;                  // 8,388,608 (q + stage4 Y)
    float* pbuf = qbuf + (long)8388608;                 // 4,194,304
    // knn scratch lives inside pbuf (disjoint lifetime with p-values)
    float* knnd = pbuf;                                 // 1,310,720
    int*   knni = (int*)(pbuf + 1310720);               // 1,310,720
    int*   idxb = (int*)(pbuf + 4194304);               // 327,680 ints
    float* xt   = (float*)(idxb + 327680);              // 49,152
    float* xx   = xt + 49152;                           // 16,384
    float* Atq  = xx + 16384;                           // 262,144
    float* Atp  = Atq + 262144;                         // 262,144
    float* shf  = Atp + 262144;                         // 512
    float* ymax = shf + 512;                            // 2,048

    // ---- prep ----
    prep_xt_kernel<<<dim3(192), dim3(256), 0, stream>>>(x, xt);

    // ---- stage 0: knn on coords (C=3) ----
    sqnorm_kernel<<<dim3(16, NB), dim3(256), 0, stream>>>(xt, xx, 3, (long)3 * N_PTS);
    fused_knn2<3><<<dim3(N_PTS / 64, 4, NB), dim3(256), 0, stream>>>(
        xt, xx, knnd, knni, (long)3 * N_PTS);
    knn_merge4<<<dim3(64), dim3(256), 0, stream>>>(knnd, knni, idxb);
    edge0_kernel<<<dim3(N_PTS / 4, NB), dim3(64, 4), 0, stream>>>(
        xt, idxb, W[0], g[0], bb[0], m[0], v[0], cat);

    // ---- stages 1..3 ----
    const int Cs_[3]   = {64, 64, 128};
    const int co_[3]   = {64, 128, 256};
    const int inO_[3]  = {0, 64, 128};
    const int outO_[3] = {64, 128, 256};
    for (int s = 0; s < 3; s++) {
        int C = Cs_[s], cout = co_[s];
        const float* F = cat + (long)inO_[s] * N_PTS;   // batch stride 512*N
        sqnorm_kernel<<<dim3(16, NB), dim3(256), 0, stream>>>(F, xx, C, (long)512 * N_PTS);
        if (C == 64)
            fused_knn2<64><<<dim3(N_PTS / 64, 4, NB), dim3(256), 0, stream>>>(
                F, xx, knnd, knni, (long)512 * N_PTS);
        else
            fused_knn2<128><<<dim3(N_PTS / 64, 4, NB), dim3(256), 0, stream>>>(
                F, xx, knnd, knni, (long)512 * N_PTS);
        knn_merge4<<<dim3(64), dim3(256), 0, stream>>>(knnd, knni, idxb);

        int li = s + 1;
        fold_edge_kernel<<<dim3((C * cout + 255) / 256), dim3(256), 0, stream>>>(
            W[li], g[li], bb[li], m[li], v[li], Atq, Atp, shf, C, cout);
        // q: Out[j][o] point-major
        gemm_kmajor<<<dim3(N_PTS / 64, cout / 64, NB), dim3(256), 0, stream>>>(
            F, Atq, qbuf, nullptr,
            C, N_PTS, cout, cout, (long)512 * N_PTS, 0, (long)N_PTS * cout, 0);
        // p: Out[i][o] + shift[o]
        gemm_kmajor<<<dim3(N_PTS / 64, cout / 64, NB), dim3(256), 0, stream>>>(
            F, Atp, pbuf, shf,
            C, N_PTS, cout, cout, (long)512 * N_PTS, 0, (long)N_PTS * cout, 1);
        gather_max_kernel<<<dim3(N_PTS / 4, NB), dim3(64, 4), 0, stream>>>(
            qbuf, pbuf, idxb, cat, cout, outO_[s]);
    }

    // ---- stage 4: pointwise conv + bn + lrelu, channel-major out ----
    fold_plain_kernel<<<dim3((512 * 512 + 255) / 256), dim3(256), 0, stream>>>(
        W[4], g[4], bb[4], m[4], v[4], Atq, shf, 512, 512);
    gemm_kmajor<<<dim3(512 / 64, N_PTS / 64, NB), dim3(256), 0, stream>>>(
        Atq, cat, qbuf, shf,
        512, 512, N_PTS, N_PTS, 0, (long)512 * N_PTS, (long)512 * N_PTS, 2);

    // ---- global max + head ----
    rowmax_kernel<<<dim3(512, NB), dim3(256), 0, stream>>>(qbuf, ymax);
    head_kernel<<<dim3(NB), dim3(128), 0, stream>>>(ymax, We, Wh, bh, out);
}